// Round 2
// baseline (2731.228 us; speedup 1.0000x reference)
//
#include <hip/hip_runtime.h>
#include <math.h>

#define DIMX 128
#define HIDN 256
#define NSTEPS 100
#define BATCHN 4096
#define RROWS 16          // rows per block
#define TTHREADS 512      // 8 waves
#define LPAD 20           // padded row stride (floats) for transposed LDS tiles

__device__ __forceinline__ float gelu_f(float x) {
    // jax.nn.gelu approximate=True: 0.5*x*(1+tanh(sqrt(2/pi)*(x+0.044715 x^3)))
    // == x * sigmoid(2*sqrt(2/pi)*(x+0.044715 x^3)); safe at both tails.
    float x3 = x * x * x;
    float e = __expf(-1.5957691216057308f * (x + 0.044715f * x3));
    return x / (1.0f + e);
}

__global__ __launch_bounds__(TTHREADS) void sde_kernel(
    const float* __restrict__ noise,
    const float* __restrict__ W1, const float* __restrict__ b1,
    const float* __restrict__ W2, const float* __restrict__ b2,
    const float* __restrict__ W3, const float* __restrict__ b3,
    float* __restrict__ out)
{
    // transposed activation tiles: [k][row], padded to LPAD to tame write conflicts
    __shared__ float xs_t[DIMX][LPAD];   // state x (16 rows live in [k][0..15])
    __shared__ float h1_t[HIDN][LPAD];
    __shared__ float h2_t[HIDN][LPAD];
    __shared__ float us[RROWS][DIMX];    // u in row-major for update/reduction
    __shared__ float a1s[RROWS], a2s[RROWS], r1s[RROWS], r2s[RROWS];

    const int tid  = threadIdx.x;
    const int row0 = blockIdx.x * RROWS;

    float* ts_out = out + (size_t)(NSTEPS + 1) * BATCHN * 130;
    if (blockIdx.x == 0 && tid <= NSTEPS) ts_out[tid] = (float)tid * 0.01f;

    // zero init state + traj[0] rows
    for (int i = tid; i < DIMX * LPAD; i += TTHREADS) ((float*)xs_t)[i] = 0.f;
    if (tid < RROWS) { a1s[tid] = 0.f; a2s[tid] = 0.f; }
    {
        float* t0 = out + (size_t)row0 * 130;
        for (int i = tid; i < RROWS * 130; i += TTHREADS) t0[i] = 0.f;
    }

    // phase-1/2 mapping: column cH (0..255), row half rh (0..1) -> rows r0..r0+7
    const int cH = tid & (HIDN - 1);
    const int rh = tid >> 8;
    const int r0 = rh * 8;
    // phase-3 mapping: column cD (0..127), row quad rq (0..3) -> rows rq*4..+3
    const int cD = tid & (DIMX - 1);
    const int rq = tid >> 7;
    // update mapping: 32 lanes per row
    const int urow = tid >> 5;
    const int ul   = tid & 31;

    const float b1c = b1[cH];
    const float b2c = b2[cH];
    const float b3c = b3[cD];
    const float w1t = W1[DIMX * HIDN + cH];   // time-row weight (constant)

    __syncthreads();

    for (int step = 0; step < NSTEPS; ++step) {
        float t    = (float)step * 0.01f;
        float tn   = (float)(step + 1) * 0.01f;
        float dt   = tn - t;
        float sqdt = sqrtf(dt);

        // ---- phase 1: h1 = gelu([x, t] @ W1 + b1) ----
        {
            float acc[8];
            float init = fmaf(t, w1t, b1c);
            #pragma unroll
            for (int j = 0; j < 8; ++j) acc[j] = init;
            #pragma unroll 4
            for (int k = 0; k < DIMX; ++k) {
                float w = W1[k * HIDN + cH];               // coalesced, L2-hot
                const float4* xr = (const float4*)&xs_t[k][r0];  // wave-uniform b128 broadcast
                float4 xa = xr[0], xb = xr[1];
                acc[0] = fmaf(xa.x, w, acc[0]); acc[1] = fmaf(xa.y, w, acc[1]);
                acc[2] = fmaf(xa.z, w, acc[2]); acc[3] = fmaf(xa.w, w, acc[3]);
                acc[4] = fmaf(xb.x, w, acc[4]); acc[5] = fmaf(xb.y, w, acc[5]);
                acc[6] = fmaf(xb.z, w, acc[6]); acc[7] = fmaf(xb.w, w, acc[7]);
            }
            float4 g0 = make_float4(gelu_f(acc[0]), gelu_f(acc[1]), gelu_f(acc[2]), gelu_f(acc[3]));
            float4 g1 = make_float4(gelu_f(acc[4]), gelu_f(acc[5]), gelu_f(acc[6]), gelu_f(acc[7]));
            *(float4*)&h1_t[cH][r0]     = g0;
            *(float4*)&h1_t[cH][r0 + 4] = g1;
        }
        __syncthreads();

        // ---- phase 2: h2 = gelu(h1 @ W2 + b2) ----
        {
            float acc[8];
            #pragma unroll
            for (int j = 0; j < 8; ++j) acc[j] = b2c;
            #pragma unroll 4
            for (int k = 0; k < HIDN; ++k) {
                float w = W2[k * HIDN + cH];
                const float4* hr = (const float4*)&h1_t[k][r0];
                float4 ha = hr[0], hb = hr[1];
                acc[0] = fmaf(ha.x, w, acc[0]); acc[1] = fmaf(ha.y, w, acc[1]);
                acc[2] = fmaf(ha.z, w, acc[2]); acc[3] = fmaf(ha.w, w, acc[3]);
                acc[4] = fmaf(hb.x, w, acc[4]); acc[5] = fmaf(hb.y, w, acc[5]);
                acc[6] = fmaf(hb.z, w, acc[6]); acc[7] = fmaf(hb.w, w, acc[7]);
            }
            float4 g0 = make_float4(gelu_f(acc[0]), gelu_f(acc[1]), gelu_f(acc[2]), gelu_f(acc[3]));
            float4 g1 = make_float4(gelu_f(acc[4]), gelu_f(acc[5]), gelu_f(acc[6]), gelu_f(acc[7]));
            *(float4*)&h2_t[cH][r0]     = g0;
            *(float4*)&h2_t[cH][r0 + 4] = g1;
        }
        __syncthreads();

        // ---- phase 3: u = h2 @ W3 + b3 ----
        {
            float acc[4];
            #pragma unroll
            for (int j = 0; j < 4; ++j) acc[j] = b3c;
            #pragma unroll 4
            for (int k = 0; k < HIDN; ++k) {
                float w = W3[k * DIMX + cD];
                const float4* hr = (const float4*)&h2_t[k][rq * 4];  // b128 broadcast
                float4 ha = hr[0];
                acc[0] = fmaf(ha.x, w, acc[0]); acc[1] = fmaf(ha.y, w, acc[1]);
                acc[2] = fmaf(ha.z, w, acc[2]); acc[3] = fmaf(ha.w, w, acc[3]);
            }
            #pragma unroll
            for (int j = 0; j < 4; ++j) us[rq * 4 + j][cD] = acc[j];
        }
        __syncthreads();

        // ---- update: x += u*dt + dW; a1 += sum(u*dW); a2 += (sum(u^2)/2)*dt ----
        {
            float* traj1 = out + ((size_t)(step + 1) * BATCHN + row0) * 130;
            const float* nz = noise + ((size_t)step * BATCHN + row0 + urow) * DIMX;
            float s_uu = 0.f, s_udw = 0.f;
            #pragma unroll
            for (int j = 0; j < 4; ++j) {
                int c = ul + 32 * j;
                float u    = us[urow][c];
                float dW   = sqdt * nz[c];
                float xold = xs_t[c][urow];
                float xnew = fmaf(u, dt, xold) + dW;
                s_uu  = fmaf(u, u, s_uu);
                s_udw = fmaf(u, dW, s_udw);
                xs_t[c][urow] = xnew;
                traj1[urow * 130 + c] = xnew;
            }
            #pragma unroll
            for (int off = 16; off >= 1; off >>= 1) {
                s_uu  += __shfl_down(s_uu,  off);
                s_udw += __shfl_down(s_udw, off);
            }
            if (ul == 0) { r1s[urow] = s_udw; r2s[urow] = s_uu; }
            __syncthreads();
            if (tid < RROWS) {
                float a1 = a1s[tid] + r1s[tid];
                float a2 = fmaf(r2s[tid] * 0.5f, dt, a2s[tid]);
                a1s[tid] = a1; a2s[tid] = a2;
                traj1[tid * 130 + 128] = a1;
                traj1[tid * 130 + 129] = a2;
            }
            __syncthreads();   // state consistent before next step's phase 1
        }
    }
}

extern "C" void kernel_launch(void* const* d_in, const int* in_sizes, int n_in,
                              void* d_out, int out_size, void* d_ws, size_t ws_size,
                              hipStream_t stream) {
    const float* noise = (const float*)d_in[0];
    const float* W1    = (const float*)d_in[1];
    const float* b1    = (const float*)d_in[2];
    const float* W2    = (const float*)d_in[3];
    const float* b2    = (const float*)d_in[4];
    const float* W3    = (const float*)d_in[5];
    const float* b3    = (const float*)d_in[6];
    float* out = (float*)d_out;

    dim3 grid(BATCHN / RROWS);   // 256 blocks -> 1 per CU
    dim3 block(TTHREADS);        // 512 threads = 8 waves
    hipLaunchKernelGGL(sde_kernel, grid, block, 0, stream,
                       noise, W1, b1, W2, b2, W3, b3, out);
}

// Round 3
// 1816.184 us; speedup vs baseline: 1.5038x; 1.5038x over previous
//
#include <hip/hip_runtime.h>
#include <math.h>

#define NSTEPS 100
#define BATCHN 4096

typedef __attribute__((ext_vector_type(8))) short bf16x8;   // 8 x bf16 (4 VGPRs)
typedef __attribute__((ext_vector_type(4))) float f32x4;

#define MFMA16(a, b, c) __builtin_amdgcn_mfma_f32_16x16x32_bf16(a, b, c, 0, 0, 0)

__device__ __forceinline__ unsigned short rne_bf16(float x) {
    unsigned u = __float_as_uint(x);
    return (unsigned short)((u + 0x7FFFu + ((u >> 16) & 1u)) >> 16);
}
__device__ __forceinline__ float bf16_f(unsigned short h) {
    return __uint_as_float(((unsigned)h) << 16);
}
__device__ __forceinline__ float gelu_f(float x) {
    // jax.nn.gelu approximate=True via sigmoid form; tail-safe.
    float x3 = x * x * x;
    float e = __expf(-1.5957691216057308f * (x + 0.044715f * x3));
    return x / (1.0f + e);
}

// ---------------------------------------------------------------------------
// Prep: swizzle W1/W2/W3 (fp32) into bf16 hi/lo B-fragment layout in ws.
// Frag-pair fp: 0..79 = W1[nt=16][kt=5], 80..207 = W2[16][8], 208..271 = W3[8][8].
// Pair base (shorts) = fp*1024; hi frag lane l at +l*8, lo at +512+l*8.
// B-fragment (16x16x32): lane l holds B[k = kt*32 + (l>>4)*8 + j][n = nt*16 + (l&15)].
// W1 rows k>=129 are zero-padded (col 128 of the input is t; 129..159 pad).
// ---------------------------------------------------------------------------
__global__ __launch_bounds__(256) void prep_weights(
    const float* __restrict__ W1, const float* __restrict__ W2,
    const float* __restrict__ W3, short* __restrict__ ws)
{
    int g = blockIdx.x * 256 + threadIdx.x;
    if (g >= 272 * 64) return;
    int fp = g >> 6, l = g & 63;
    int m = l & 15, kq = (l >> 4) * 8;
    const float* W; int ndim, kdim, nt, kt;
    if (fp < 80)       { W = W1; ndim = 256; kdim = 129; nt = fp / 5;         kt = fp % 5; }
    else if (fp < 208) { W = W2; ndim = 256; kdim = 256; nt = (fp - 80) >> 3;  kt = (fp - 80) & 7; }
    else               { W = W3; ndim = 128; kdim = 256; nt = (fp - 208) >> 3; kt = (fp - 208) & 7; }
    int n = nt * 16 + m;
    bf16x8 vh, vl;
    #pragma unroll
    for (int j = 0; j < 8; ++j) {
        int k = kt * 32 + kq + j;
        float v = (k < kdim) ? W[k * ndim + n] : 0.f;
        unsigned short h = rne_bf16(v);
        float r = v - bf16_f(h);
        vh[j] = (short)h;
        vl[j] = (short)rne_bf16(r);
    }
    short* base = ws + (size_t)fp * 1024 + l * 8;
    *(bf16x8*)base = vh;
    *(bf16x8*)(base + 512) = vl;
}

// ---------------------------------------------------------------------------
// Main persistent kernel: 256 blocks (1/CU) x 1024 threads (16 waves), M=16
// rows/block, 100 steps. Activations live in LDS in A-fragment layout
// (bf16 hi/lo); weights stream from ws (L2-resident). 3-product bf16 split.
// ---------------------------------------------------------------------------
__global__ __launch_bounds__(1024) void sde_mfma_kernel(
    const float* __restrict__ noise,
    const float* __restrict__ b1, const float* __restrict__ b2,
    const float* __restrict__ b3, const short* __restrict__ ws,
    float* __restrict__ out)
{
    // A-frag buffers: [kt][s=hi/lo][lane=64][8 bf16]  (stride 512 shorts per (kt,s))
    __shared__ short xa [5 * 2 * 512];   // x plus t plus pad (K=160)
    __shared__ short h1a[8 * 2 * 512];   // h1 (K=256)
    __shared__ short h2a[8 * 2 * 512];   // h2 (K=256)
    __shared__ float p3  [8 * 64 * 4];   // phase-3 split-K partials
    __shared__ float part[8 * 16 * 2];   // per-wave row partials (udw, uu)
    __shared__ float xm  [16 * 132];     // fp32 master state x[16][128] (pad 132)

    const int tid  = threadIdx.x;
    const int w    = tid >> 6;          // wave 0..15
    const int l    = tid & 63;          // lane
    const int m16  = l & 15;
    const int q    = l >> 4;            // quad
    const int row0 = blockIdx.x * 16;

    // init
    for (int i = tid; i < 5 * 2 * 512; i += 1024) xa[i] = 0;
    for (int i = tid; i < 16 * 132;    i += 1024) xm[i] = 0.f;
    {   // traj[0] rows for this block (x=0, a1=a2=0)
        float* t0 = out + (size_t)row0 * 130;
        for (int i = tid; i < 16 * 130; i += 1024) t0[i] = 0.f;
    }
    if (blockIdx.x == 0 && tid <= NSTEPS)
        out[(size_t)(NSTEPS + 1) * BATCHN * 130 + tid] = (float)tid * 0.01f;

    float a1 = 0.f, a2 = 0.f;                 // live in tid<16 threads
    const float bias1 = b1[w * 16 + m16];
    const float bias2 = b2[w * 16 + m16];
    const int nt3   = w & 7;
    const int khalf = w >> 3;
    const float bias3 = b3[nt3 * 16 + m16];

    __syncthreads();

    for (int step = 0; step < NSTEPS; ++step) {
        const float tn   = (float)(step + 1) * 0.01f;
        const float t    = (float)step * 0.01f;
        const float dt   = tn - t;
        const float sqdt = sqrtf(dt);

        // ---- phase 1: h1 = gelu([x,t,0...] @ W1 + b1), nt = w, K-tiles 5 ----
        {
            f32x4 acc = {0.f, 0.f, 0.f, 0.f};
            #pragma unroll
            for (int kt = 0; kt < 5; ++kt) {
                bf16x8 ah = *(const bf16x8*)&xa[(kt * 2 + 0) * 512 + l * 8];
                bf16x8 al = *(const bf16x8*)&xa[(kt * 2 + 1) * 512 + l * 8];
                const short* bp = ws + (size_t)(w * 5 + kt) * 1024 + l * 8;
                bf16x8 bh = *(const bf16x8*)bp;
                bf16x8 bl = *(const bf16x8*)(bp + 512);
                acc = MFMA16(ah, bh, acc);
                acc = MFMA16(al, bh, acc);
                acc = MFMA16(ah, bl, acc);
            }
            const int ktw   = w >> 1;
            const int gbase = ((w & 1) * 2 + (m16 >> 3)) * 16;
            const int jj    = m16 & 7;
            #pragma unroll
            for (int r = 0; r < 4; ++r) {
                float h = gelu_f(acc[r] + bias1);
                unsigned short hh = rne_bf16(h);
                unsigned short hl = rne_bf16(h - bf16_f(hh));
                int lp = gbase + q * 4 + r;
                h1a[(ktw * 2 + 0) * 512 + lp * 8 + jj] = (short)hh;
                h1a[(ktw * 2 + 1) * 512 + lp * 8 + jj] = (short)hl;
            }
        }
        __syncthreads();

        // ---- phase 2: h2 = gelu(h1 @ W2 + b2), nt = w, K-tiles 8 ----
        {
            f32x4 acc = {0.f, 0.f, 0.f, 0.f};
            #pragma unroll
            for (int kt = 0; kt < 8; ++kt) {
                bf16x8 ah = *(const bf16x8*)&h1a[(kt * 2 + 0) * 512 + l * 8];
                bf16x8 al = *(const bf16x8*)&h1a[(kt * 2 + 1) * 512 + l * 8];
                const short* bp = ws + (size_t)(80 + w * 8 + kt) * 1024 + l * 8;
                bf16x8 bh = *(const bf16x8*)bp;
                bf16x8 bl = *(const bf16x8*)(bp + 512);
                acc = MFMA16(ah, bh, acc);
                acc = MFMA16(al, bh, acc);
                acc = MFMA16(ah, bl, acc);
            }
            const int ktw   = w >> 1;
            const int gbase = ((w & 1) * 2 + (m16 >> 3)) * 16;
            const int jj    = m16 & 7;
            #pragma unroll
            for (int r = 0; r < 4; ++r) {
                float h = gelu_f(acc[r] + bias2);
                unsigned short hh = rne_bf16(h);
                unsigned short hl = rne_bf16(h - bf16_f(hh));
                int lp = gbase + q * 4 + r;
                h2a[(ktw * 2 + 0) * 512 + lp * 8 + jj] = (short)hh;
                h2a[(ktw * 2 + 1) * 512 + lp * 8 + jj] = (short)hl;
            }
        }
        __syncthreads();

        // ---- phase 3: u = h2 @ W3 + b3; split-K across wave pairs ----
        f32x4 acc3 = {0.f, 0.f, 0.f, 0.f};
        {
            const int kt0 = khalf * 4;
            #pragma unroll
            for (int kk = 0; kk < 4; ++kk) {
                int kt = kt0 + kk;
                bf16x8 ah = *(const bf16x8*)&h2a[(kt * 2 + 0) * 512 + l * 8];
                bf16x8 al = *(const bf16x8*)&h2a[(kt * 2 + 1) * 512 + l * 8];
                const short* bp = ws + (size_t)(208 + nt3 * 8 + kt) * 1024 + l * 8;
                bf16x8 bh = *(const bf16x8*)bp;
                bf16x8 bl = *(const bf16x8*)(bp + 512);
                acc3 = MFMA16(ah, bh, acc3);
                acc3 = MFMA16(al, bh, acc3);
                acc3 = MFMA16(ah, bl, acc3);
            }
            if (khalf) *(f32x4*)&p3[(nt3 * 64 + l) * 4] = acc3;
        }
        __syncthreads();

        // ---- update (waves 0-7): x += u*dt + dW; partial sums; refresh xa ----
        if (!khalf) {
            f32x4 o = *(const f32x4*)&p3[(nt3 * 64 + l) * 4];
            const int c = nt3 * 16 + m16;
            const float* nz = noise + ((size_t)step * BATCHN + row0) * 128;
            float* tro = out + ((size_t)(step + 1) * BATCHN + row0) * 130;
            const int ktx = c >> 5;
            const int lpb = ((c & 31) >> 3) * 16;
            const int jx  = c & 7;
            #pragma unroll
            for (int r = 0; r < 4; ++r) {
                int row = q * 4 + r;
                float u  = acc3[r] + o[r] + bias3;
                float dW = sqdt * nz[row * 128 + c];
                float xo = xm[row * 132 + c];
                float xn = fmaf(u, dt, xo) + dW;
                xm[row * 132 + c] = xn;
                tro[row * 130 + c] = xn;
                unsigned short xh = rne_bf16(xn);
                unsigned short xl = rne_bf16(xn - bf16_f(xh));
                int lp = lpb + row;
                xa[(ktx * 2 + 0) * 512 + lp * 8 + jx] = (short)xh;
                xa[(ktx * 2 + 1) * 512 + lp * 8 + jx] = (short)xl;
                float udw = u * dW, uu = u * u;
                udw += __shfl_xor(udw, 1);  uu += __shfl_xor(uu, 1);
                udw += __shfl_xor(udw, 2);  uu += __shfl_xor(uu, 2);
                udw += __shfl_xor(udw, 4);  uu += __shfl_xor(uu, 4);
                udw += __shfl_xor(udw, 8);  uu += __shfl_xor(uu, 8);
                if (m16 == 0) {
                    part[(w * 16 + row) * 2 + 0] = udw;
                    part[(w * 16 + row) * 2 + 1] = uu;
                }
            }
        }
        __syncthreads();

        // ---- final reduce + a1/a2 + t_next (threads 0-15, one per row) ----
        if (tid < 16) {
            float sudw = 0.f, suu = 0.f;
            #pragma unroll
            for (int wv = 0; wv < 8; ++wv) {
                sudw += part[(wv * 16 + tid) * 2 + 0];
                suu  += part[(wv * 16 + tid) * 2 + 1];
            }
            a1 += sudw;                       // gamma = 1
            a2 = fmaf(suu * 0.5f, dt, a2);
            float* tro = out + ((size_t)(step + 1) * BATCHN + row0 + tid) * 130;
            tro[128] = a1;
            tro[129] = a2;
            unsigned short th = rne_bf16(tn);
            unsigned short tl = rne_bf16(tn - bf16_f(th));
            xa[(4 * 2 + 0) * 512 + tid * 8 + 0] = (short)th;  // k=128 slot = t
            xa[(4 * 2 + 1) * 512 + tid * 8 + 0] = (short)tl;
        }
        __syncthreads();
    }
}

extern "C" void kernel_launch(void* const* d_in, const int* in_sizes, int n_in,
                              void* d_out, int out_size, void* d_ws, size_t ws_size,
                              hipStream_t stream) {
    const float* noise = (const float*)d_in[0];
    const float* W1    = (const float*)d_in[1];
    const float* b1    = (const float*)d_in[2];
    const float* W2    = (const float*)d_in[3];
    const float* b2    = (const float*)d_in[4];
    const float* W3    = (const float*)d_in[5];
    const float* b3    = (const float*)d_in[6];
    float* out = (float*)d_out;
    short* ws  = (short*)d_ws;   // needs 272*2048 = 557056 bytes

    hipLaunchKernelGGL(prep_weights, dim3(68), dim3(256), 0, stream, W1, W2, W3, ws);
    hipLaunchKernelGGL(sde_mfma_kernel, dim3(BATCHN / 16), dim3(1024), 0, stream,
                       noise, b1, b2, b3, ws, out);
}